// Round 3
// 838.310 us; speedup vs baseline: 1.0144x; 1.0144x over previous
//
#include <hip/hip_runtime.h>
#include <cstdint>

#define CC 512
#define AA 256

typedef __bf16 bf16x8 __attribute__((ext_vector_type(8)));
typedef float f32x16 __attribute__((ext_vector_type(16)));
typedef unsigned short u16x8 __attribute__((ext_vector_type(8)));

__device__ __forceinline__ unsigned short bf(float f) {
  return __builtin_bit_cast(unsigned short, (__bf16)f);  // v_cvt RNE, 2/op packed
}

__device__ __forceinline__ bf16x8 cvt8(float4 lo, float4 hi) {
  bf16x8 r;
  r[0] = (__bf16)lo.x; r[1] = (__bf16)lo.y; r[2] = (__bf16)lo.z; r[3] = (__bf16)lo.w;
  r[4] = (__bf16)hi.x; r[5] = (__bf16)hi.y; r[6] = (__bf16)hi.z; r[7] = (__bf16)hi.w;
  return r;
}

// async global->LDS DMA, 16 B/lane (writes wave-uniform base + lane*16)
__device__ __forceinline__ void dma16(const void* g, void* l) {
  __builtin_amdgcn_global_load_lds(
      (const __attribute__((address_space(1))) unsigned int*)g,
      (__attribute__((address_space(3))) unsigned int*)l, 16, 0, 0);
}

// swizzled LDS read: byte = (row*128 + kbyte) ^ ((row&7)<<4)  -- conflict-free b128
__device__ __forceinline__ bf16x8 ldsw(const unsigned short* b, int row, int kbyte) {
  return *(const bf16x8*)((const char*)b + (((row * 128) + kbyte) ^ ((row & 7) << 4)));
}

// ---------------- prep: attn2 = Ua.q + Ua_b + Wa_b ; Wa -> swizzled bf16 ; zero ctx
__global__ __launch_bounds__(256) void prep_kernel(
    const float* __restrict__ q,
    const float* __restrict__ Wa_w,
    const float* __restrict__ Wa_b,
    const float* __restrict__ Ua_w,
    const float* __restrict__ Ua_b,
    unsigned short* __restrict__ wa_swz,
    float* __restrict__ attn2,
    float* __restrict__ out_ctx) {
  const int blk = blockIdx.x, t = threadIdx.x;
  if (blk < 64) {
    // quad-coalesced Ua.q: 4 lanes per a-row -> 64-B line use, q staged in LDS
    __shared__ float qs[CC];
    const int b = blk;
    qs[t] = q[(size_t)b * CC + t];
    qs[t + 256] = q[(size_t)b * CC + t + 256];
    __syncthreads();
    const int qd = t & 3, ar = t >> 2;
    const float4* qr = (const float4*)qs;
#pragma unroll
    for (int ao = 0; ao < 4; ++ao) {
      const int a = ao * 64 + ar;
      const float4* ur = (const float4*)(Ua_w + (size_t)a * CC);
      float acc = 0.f;
#pragma unroll 8
      for (int i = 0; i < 32; ++i) {
        float4 u = ur[qd + i * 4];
        float4 qq = qr[qd + i * 4];
        acc += u.x * qq.x + u.y * qq.y + u.z * qq.z + u.w * qq.w;
      }
      acc += __shfl_xor(acc, 1);
      acc += __shfl_xor(acc, 2);
      if (qd == 0) attn2[b * AA + a] = acc + Ua_b[a] + Wa_b[a];
    }
  } else if (blk < 128) {
    // Wa fp32 -> bf16, stored PRE-SWIZZLED per 64-wide ko tile so a linear
    // global_load_lds lands it in XOR-swizzled LDS layout (m173 pattern).
    // u16 index within tile: (n*64 + j) ^ ((n&7)<<3)
    const int e = (blk - 64) * 2048 + t * 8;
    const int n = e >> 9, k = e & 511;
    const int ko = k >> 6, j = k & 63;
    float4 lo = *(const float4*)(Wa_w + e);
    float4 hi = *(const float4*)(Wa_w + e + 4);
    u16x8 hv;
    hv[0] = bf(lo.x); hv[1] = bf(lo.y); hv[2] = bf(lo.z); hv[3] = bf(lo.w);
    hv[4] = bf(hi.x); hv[5] = bf(hi.y); hv[6] = bf(hi.z); hv[7] = bf(hi.w);
    const int dst = ko * 16384 + ((n * 64 + j) ^ ((n & 7) << 3));
    *(u16x8*)(wa_swz + dst) = hv;
  } else {
    const int base = (blk - 128) * 512 + t * 2;  // zero 32768 context floats
    out_ctx[base] = 0.f; out_ctx[base + 1] = 0.f;
  }
}

// ---------------- scores: s[r] = va . tanh(keys[r].Wa^T + attn2[b]) + va_b ----
// M=128 rows/block (2 pixels x 64 b), N=256 (all A), K=512 in 8 x BK=64.
// 4 waves, each OWNS 32 rows x 256 cols: A-frags straight from global fp32
// (no A LDS, per-lane 16B pairs into 64-B lines), cvt in-reg; B via DMA from
// pre-swizzled wa_swz into double-buffered LDS. One barrier per K-step; the
// syncthreads vmcnt(0) drain retires the in-flight ko+1 loads issued under
// MFMA(ko).
__global__ __launch_bounds__(256, 2) void scores_kernel(
    const float* __restrict__ keys,
    const unsigned short* __restrict__ wa_swz,
    const float* __restrict__ attn2,
    const float* __restrict__ va_w,
    const float* __restrict__ va_b,
    float* __restrict__ scores) {
  __shared__ __align__(16) unsigned short Bs[2][256 * 64];  // 64 KiB -> 2 blk/CU

  const int t = threadIdx.x;
  const int w = t >> 6, lane = t & 63;
  const int m32 = lane & 31, kg = lane >> 5;
  const long r0 = (long)blockIdx.x * 128;
  const size_t arow = (size_t)(r0 + w * 32 + m32) * CC;  // this lane's keys row

  f32x16 acc[8];
#pragma unroll
  for (int i = 0; i < 8; ++i)
#pragma unroll
    for (int e = 0; e < 16; ++e) acc[i][e] = 0.f;

  float4 areg[8];
  // prologue: A(0) regs + DMA B(0) -> Bs[0]
#pragma unroll
  for (int kk = 0; kk < 4; ++kk)
#pragma unroll
    for (int h = 0; h < 2; ++h)
      areg[kk * 2 + h] = *(const float4*)(keys + arow + kk * 16 + kg * 8 + h * 4);
  {
    const char* gB = (const char*)wa_swz;
    char* lB = (char*)&Bs[0][0];
#pragma unroll
    for (int i = 0; i < 8; ++i) {
      const int c = (w * 8 + i) * 1024;
      dma16(gB + c + lane * 16, lB + c);
    }
  }

  int cur = 0;
#pragma unroll 2
  for (int ko = 0; ko < 8; ++ko) {
    __syncthreads();  // drains DMA(ko) + areg(ko) loads; fences Bs[cur^1] readers
    bf16x8 af[4];
#pragma unroll
    for (int kk = 0; kk < 4; ++kk) af[kk] = cvt8(areg[kk * 2], areg[kk * 2 + 1]);
    if (ko < 7) {  // issue next tile; in flight under MFMA(ko)
      const int kb = (ko + 1) * 64;
#pragma unroll
      for (int kk = 0; kk < 4; ++kk)
#pragma unroll
        for (int h = 0; h < 2; ++h)
          areg[kk * 2 + h] =
              *(const float4*)(keys + arow + kb + kk * 16 + kg * 8 + h * 4);
      const char* gB = (const char*)wa_swz + (size_t)(ko + 1) * 32768;
      char* lB = (char*)&Bs[cur ^ 1][0];
#pragma unroll
      for (int i = 0; i < 8; ++i) {
        const int c = (w * 8 + i) * 1024;
        dma16(gB + c + lane * 16, lB + c);
      }
    }
    const unsigned short* B0 = &Bs[cur][0];
#pragma unroll
    for (int kk = 0; kk < 4; ++kk) {
      const int kbyte = kk * 32 + kg * 16;
#pragma unroll
      for (int nt = 0; nt < 8; ++nt) {
        bf16x8 bfr = ldsw(B0, nt * 32 + m32, kbyte);
        acc[nt] = __builtin_amdgcn_mfma_f32_32x32x16_bf16(af[kk], bfr, acc[nt], 0, 0, 0);
      }
    }
    cur ^= 1;
  }

  // ---- epilogue: tanh(acc + attn2[b][a]) * va[a], reduce over a ----
  // C/D layout (m74/m101): col = nt*32 + m32; row = rbase + (r&3)+8*(r>>2).
  // Wave covers all 256 cols -> shuffle-reduce over m32 gives final score.
  float ps[16];
#pragma unroll
  for (int r = 0; r < 16; ++r) ps[r] = 0.f;
  const int rbase = w * 32 + 4 * kg;
#pragma unroll
  for (int nt = 0; nt < 8; ++nt) {
    const int col = nt * 32 + m32;
    const float vv = va_w[col];
#pragma unroll
    for (int r = 0; r < 16; ++r) {
      const int row = rbase + (r & 3) + 8 * (r >> 2);
      float x = acc[nt][r] + attn2[(row & 63) * AA + col];
      float ax = fabsf(x);
      float e2 = __expf(-2.f * ax);
      float th = (1.f - e2) / (1.f + e2);
      ps[r] += copysignf(th, x) * vv;
    }
  }
#pragma unroll
  for (int off = 1; off <= 16; off <<= 1)
#pragma unroll
    for (int r = 0; r < 16; ++r) ps[r] += __shfl_xor(ps[r], off);
  if (m32 == 0) {
    const float vb = va_b[0];
#pragma unroll
    for (int r = 0; r < 16; ++r) {
      const int row = rbase + (r & 3) + 8 * (r >> 2);
      scores[r0 + row] = ps[r] + vb;
    }
  }
}

// ---------------- softmax over P per b; writes weights to d_out+32768 --------
__global__ void softmax_kernel(const float* __restrict__ scores,
                               float* __restrict__ out) {
  const int b = blockIdx.x, t = threadIdx.x;
  const int w = t >> 6, lane = t & 63;
  __shared__ float red[4];
  float s[16];
  float m = -1e30f;
#pragma unroll
  for (int i = 0; i < 16; ++i) {
    s[i] = scores[(size_t)(t + 256 * i) * 64 + b];
    m = fmaxf(m, s[i]);
  }
#pragma unroll
  for (int off = 1; off <= 32; off <<= 1) m = fmaxf(m, __shfl_xor(m, off));
  if (lane == 0) red[w] = m;
  __syncthreads();
  m = fmaxf(fmaxf(red[0], red[1]), fmaxf(red[2], red[3]));
  float sum = 0.f;
#pragma unroll
  for (int i = 0; i < 16; ++i) { s[i] = __expf(s[i] - m); sum += s[i]; }
#pragma unroll
  for (int off = 1; off <= 32; off <<= 1) sum += __shfl_xor(sum, off);
  __syncthreads();
  if (lane == 0) red[w] = sum;
  __syncthreads();
  const float invZ = 1.f / (red[0] + red[1] + red[2] + red[3]);
  float* wout = out + 32768;
#pragma unroll
  for (int i = 0; i < 16; ++i)
    wout[(size_t)(t + 256 * i) * 64 + b] = s[i] * invZ;
}

// ---------------- context[b][c] = sum_p w[p,b] * keys[p,b,c] -----------------
// 256 threads (4 waves), two 64-row halves + LDS combine; p-chunks reversed so
// early blocks read the keys tail scores_kernel just left in L3.
__global__ __launch_bounds__(256) void context_kernel(
    const float* __restrict__ keys,
    const float* __restrict__ wts,   // d_out + 32768
    float* __restrict__ out_ctx) {   // d_out (pre-zeroed by prep)
  const int b = blockIdx.y;
  const int p0 = (31 - (int)blockIdx.x) * 128;
  const int t = threadIdx.x;
  const int half = t >> 7, c4 = t & 127;
  __shared__ float wl[128];
  __shared__ float4 part[128];
  if (t < 128) wl[t] = wts[(size_t)(p0 + t) * 64 + b];
  __syncthreads();
  float4 acc = {0.f, 0.f, 0.f, 0.f};
  const float4* kp = (const float4*)keys;
  const int jb = half * 64;
#pragma unroll 8
  for (int j = 0; j < 64; ++j) {
    const float4 kv = kp[(size_t)((p0 + jb + j) * 64 + b) * 128 + c4];
    const float wj = wl[jb + j];
    acc.x += wj * kv.x; acc.y += wj * kv.y;
    acc.z += wj * kv.z; acc.w += wj * kv.w;
  }
  if (half) part[c4] = acc;
  __syncthreads();
  if (!half) {
    const float4 o = part[c4];
    float* dst = out_ctx + b * 512 + c4 * 4;
    atomicAdd(dst + 0, acc.x + o.x);
    atomicAdd(dst + 1, acc.y + o.y);
    atomicAdd(dst + 2, acc.z + o.z);
    atomicAdd(dst + 3, acc.w + o.w);
  }
}

extern "C" void kernel_launch(void* const* d_in, const int* in_sizes, int n_in,
                              void* d_out, int out_size, void* d_ws, size_t ws_size,
                              hipStream_t stream) {
  (void)in_sizes; (void)n_in; (void)out_size; (void)ws_size;
  const float* keys = (const float*)d_in[0];
  const float* q    = (const float*)d_in[1];
  const float* Wa_w = (const float*)d_in[2];
  const float* Wa_b = (const float*)d_in[3];
  const float* Ua_w = (const float*)d_in[4];
  const float* Ua_b = (const float*)d_in[5];
  const float* va_w = (const float*)d_in[6];
  const float* va_b = (const float*)d_in[7];
  float* out = (float*)d_out;

  // workspace: Wa swizzled bf16 (262144 B) | attn2 (65536 B) | scores (1 MiB)
  unsigned short* wa_swz = (unsigned short*)d_ws;
  float* attn2  = (float*)((char*)d_ws + 262144);
  float* scores = (float*)((char*)d_ws + 262144 + 65536);

  prep_kernel<<<192, 256, 0, stream>>>(q, Wa_w, Wa_b, Ua_w, Ua_b, wa_swz, attn2, out);
  scores_kernel<<<2048, 256, 0, stream>>>(keys, wa_swz, attn2, va_w, va_b, scores);
  softmax_kernel<<<64, 256, 0, stream>>>(scores, out);
  context_kernel<<<dim3(32, 64), 256, 0, stream>>>(keys, out + 32768, out);
}